// Round 12
// baseline (844.357 us; speedup 1.0000x reference)
//
#include <hip/hip_runtime.h>

typedef __attribute__((ext_vector_type(8))) short short8;
typedef __attribute__((ext_vector_type(4))) float float4v;
typedef unsigned short u16;

#define Sdim 256
#define Udim 128
#define Hdim 512
#define MT   32       // rows per block
#define XS   392      // xh stride (u16): 384+8
#define XLS  264      // xl stride (state cols only): 256+8
#define HS   520      // h stride: 512+8
#define NW   589824   // total weight elements
#define W1_OFF 0
#define W2_OFF 196608
#define W3_OFF 458752
#define NSTEPS 21     // np-ref float32 h: floor(1/0.05f)=20 scaled + 1 unscaled

__device__ __forceinline__ float bf2f(u16 u) {
    union { unsigned int i; float f; } x; x.i = ((unsigned int)u) << 16; return x.f;
}
__device__ __forceinline__ u16 f2bf(float f) {
    union { float f; unsigned int i; } x; x.f = f;
    unsigned int r = x.i + 0x7FFFu + ((x.i >> 16) & 1u);  // RNE
    return (u16)(r >> 16);
}

__global__ void probe_dtype(const u16* __restrict__ w1, int* __restrict__ flag) {
    __shared__ int cnt;
    if (threadIdx.x == 0) cnt = 0;
    __syncthreads();
    u16 u = w1[threadIdx.x];
    int e = (u >> 7) & 0xFF;
    int pass = (u == 0) || (e >= 0x60 && e <= 0x8F);
    if (pass) atomicAdd(&cnt, 1);
    __syncthreads();
    if (threadIdx.x == 0) *flag = (cnt >= 240) ? 1 : 0;   // 1 = bf16 inputs
}

// pack W (row-major KxN) into MFMA B-frag tiles, bf16 hi plane only
// (W-lo planes proven < 1 output-ulp: R8/R10 dropped them, absmax unchanged).
__device__ __forceinline__ void pack_body(const void* __restrict__ Wraw, u16* __restrict__ hi,
                                          int K, int N, int f, int bf) {
    int KT = K >> 5;
    int lane = f & 63, tile = f >> 6;
    int kt = tile % KT, nt = tile / KT;
    int k0 = kt * 32 + ((lane >> 4) << 3);
    int n  = nt * 16 + (lane & 15);
    short8 vh;
#pragma unroll
    for (int j = 0; j < 8; ++j) {
        float wv = bf ? bf2f(((const u16*)Wraw)[(size_t)(k0 + j) * N + n])
                      : ((const float*)Wraw)[(size_t)(k0 + j) * N + n];
        vh[j] = (short)f2bf(wv);
    }
    *reinterpret_cast<short8*>(hi + (size_t)f * 8) = vh;
}

__global__ void pack_all(const void* __restrict__ W1, const void* __restrict__ W2,
                         const void* __restrict__ W3, u16* __restrict__ wh,
                         const int* __restrict__ flagp) {
    int b = blockIdx.x;
    int bf = *flagp;
    if (b < 96)
        pack_body(W1, wh + W1_OFF, 384, 512, b * 256 + threadIdx.x, bf);
    else if (b < 224)
        pack_body(W2, wh + W2_OFF, 512, 512, (b - 96) * 256 + threadIdx.x, bf);
    else
        pack_body(W3, wh + W3_OFF, 512, 256, (b - 224) * 256 + threadIdx.x, bf);
}

#define MFMA __builtin_amdgcn_mfma_f32_16x16x32_bf16

// Generic ranged GEMM (used once for the step-invariant uacc hoist).
template<int KT0, int KT, int KTB, int KTL, int NT>
__device__ __forceinline__ void mm1(const u16* ah, const u16* al, const int as, const int als,
                                    const u16* __restrict__ wh, float4v acc[2][NT]) {
#pragma unroll 2
    for (int kt = KT0; kt < KT; ++kt) {
        short8 A0 = *(const short8*)(ah + kt * 32);
        short8 A1 = *(const short8*)(ah + 16 * as + kt * 32);
        short8 A0l, A1l;
        if (kt < KTL) {
            A0l = *(const short8*)(al + kt * 32);
            A1l = *(const short8*)(al + 16 * als + kt * 32);
        }
#pragma unroll
        for (int t = 0; t < NT; ++t) {
            short8 Bh = *(const short8*)(wh + (size_t)(t * KTB + kt) * 512);
            acc[0][t] = MFMA(A0, Bh, acc[0][t], 0, 0, 0);
            acc[1][t] = MFMA(A1, Bh, acc[1][t], 0, 0, 0);
            if (kt < KTL) {
                acc[0][t] = MFMA(A0l, Bh, acc[0][t], 0, 0, 0);
                acc[1][t] = MFMA(A1l, Bh, acc[1][t], 0, 0, 0);
            }
        }
    }
}

// Phase GEMM with kt=0's B tiles preloaded (named scalars P0,P1 — issued
// before the preceding barrier, in flight across the drain). unroll 4 for
// deeper load ILP; per-acc-chain accumulation order unchanged (numerics
// identical). No loop-indexed register arrays (R7/R9: those go to scratch).
template<int KT, int KTB, int KTL, int NT>
__device__ __forceinline__ void mm1p(const u16* ah, const u16* al, const int as, const int als,
                                     const u16* __restrict__ wh, float4v acc[2][NT],
                                     short8 P0, short8 P1) {
    {   // kt = 0, B from prefetch
        short8 A0 = *(const short8*)(ah);
        short8 A1 = *(const short8*)(ah + 16 * as);
        acc[0][0] = MFMA(A0, P0, acc[0][0], 0, 0, 0);
        acc[1][0] = MFMA(A1, P0, acc[1][0], 0, 0, 0);
        if (NT > 1) {
            acc[0][1] = MFMA(A0, P1, acc[0][1], 0, 0, 0);
            acc[1][1] = MFMA(A1, P1, acc[1][1], 0, 0, 0);
        }
        if (KTL > 0) {
            short8 A0l = *(const short8*)(al);
            short8 A1l = *(const short8*)(al + 16 * als);
            acc[0][0] = MFMA(A0l, P0, acc[0][0], 0, 0, 0);
            acc[1][0] = MFMA(A1l, P0, acc[1][0], 0, 0, 0);
            if (NT > 1) {
                acc[0][1] = MFMA(A0l, P1, acc[0][1], 0, 0, 0);
                acc[1][1] = MFMA(A1l, P1, acc[1][1], 0, 0, 0);
            }
        }
    }
#pragma unroll 4
    for (int kt = 1; kt < KT; ++kt) {
        short8 A0 = *(const short8*)(ah + kt * 32);
        short8 A1 = *(const short8*)(ah + 16 * as + kt * 32);
        short8 A0l, A1l;
        if (kt < KTL) {
            A0l = *(const short8*)(al + kt * 32);
            A1l = *(const short8*)(al + 16 * als + kt * 32);
        }
#pragma unroll
        for (int t = 0; t < NT; ++t) {
            short8 Bh = *(const short8*)(wh + (size_t)(t * KTB + kt) * 512);
            acc[0][t] = MFMA(A0, Bh, acc[0][t], 0, 0, 0);
            acc[1][t] = MFMA(A1, Bh, acc[1][t], 0, 0, 0);
            if (kt < KTL) {
                acc[0][t] = MFMA(A0l, Bh, acc[0][t], 0, 0, 0);
                acc[1][t] = MFMA(A1l, Bh, acc[1][t], 0, 0, 0);
            }
        }
    }
}

__device__ __forceinline__ float silu(float v) {
    return v * __builtin_amdgcn_rcpf(1.0f + __expf(-v));
}

template<bool BF>
__device__ __forceinline__ void body(
    const void* state_raw, const void* user_raw,
    const void* b1r, const void* b2r, const void* b3r,
    const u16* __restrict__ wh_all, void* outp,
    u16* xh, u16* xl, u16* H1, u16* H2) {

    const int tid = threadIdx.x, w = tid >> 6, lane = tid & 63;   // 16 waves
    const int col16 = lane & 15, quad = lane >> 4;
    const int r0 = blockIdx.x * MT;

    // ---- one-time: user params -> xh cols 256..383 (hi only) ----
    if (tid < 512) {
        int row = tid >> 4;
        int c8 = (tid & 15) * 8;
        if (BF) {
            short8 v = *(const short8*)((const u16*)user_raw + (size_t)(r0 + row) * Udim + c8);
            *(short8*)(xh + row * XS + Sdim + c8) = v;
        } else {
            const float* up = (const float*)user_raw + (size_t)(r0 + row) * Udim + c8;
            short8 v;
#pragma unroll
            for (int j = 0; j < 8; ++j) v[j] = (short)f2bf(up[j]);
            *(short8*)(xh + row * XS + Sdim + c8) = v;
        }
    }
    // ---- biases (C-layout: depend on col only) ----
    float b1f[2], b2f[2], b3f;
#pragma unroll
    for (int t = 0; t < 2; ++t) {
        int i = w * 32 + t * 16 + col16;
        b1f[t] = BF ? bf2f(((const u16*)b1r)[i]) : ((const float*)b1r)[i];
        b2f[t] = BF ? bf2f(((const u16*)b2r)[i]) : ((const float*)b2r)[i];
    }
    {
        int i = w * 16 + col16;
        b3f = BF ? bf2f(((const u16*)b3r)[i]) : ((const float*)b3r)[i];
    }
    // ---- state: fp32 regs (C-layout, wave owns 16 cols) + hi/lo split ----
    float st[2][4];
#pragma unroll
    for (int m = 0; m < 2; ++m)
#pragma unroll
        for (int r = 0; r < 4; ++r) {
            int row = m * 16 + quad * 4 + r;
            int col = w * 16 + col16;
            float v = BF ? bf2f(((const u16*)state_raw)[(size_t)(r0 + row) * Sdim + col])
                         : ((const float*)state_raw)[(size_t)(r0 + row) * Sdim + col];
            st[m][r] = v;
            u16 h = f2bf(v);
            xh[row * XS + col] = h;
            xl[row * XLS + col] = f2bf(v - bf2f(h));
        }
    __syncthreads();

    const u16* w1h = wh_all + W1_OFF + (size_t)(w * 2) * 12 * 512 + lane * 8;
    const u16* w2h = wh_all + W2_OFF + (size_t)(w * 2) * 16 * 512 + lane * 8;
    const u16* w3h = wh_all + W3_OFF + (size_t)(w)     * 16 * 512 + lane * 8;

    const u16* aXh = xh + col16 * XS + quad * 8;
    const u16* aXl = xl + col16 * XLS + quad * 8;
    const u16* aH1 = H1 + col16 * HS + quad * 8;
    const u16* aH2 = H2 + col16 * HS + quad * 8;

    // ---- step-invariant: uacc = b1 + user@W1[256:384] (kt 8..11) ----
    float4v uacc[2][2];
#pragma unroll
    for (int m = 0; m < 2; ++m)
#pragma unroll
        for (int t = 0; t < 2; ++t) uacc[m][t] = (float4v){b1f[t], b1f[t], b1f[t], b1f[t]};
    mm1<8, 12, 12, 0, 2>(aXh, aXh, XS, XS, w1h, uacc);

    // prefetch step-0 L1's kt=0 B tiles (t*12+0 -> offsets 0, 12*512)
    short8 p0 = *(const short8*)(w1h);
    short8 p1 = *(const short8*)(w1h + 12 * 512);

    for (int step = 0; step < NSTEPS; ++step) {
        const float dt = (step == NSTEPS - 1) ? 1.0f : 0.05f;
        const bool lo_now = (step == 0) || (step == NSTEPS - 1);

        // ---- L1: silu(uacc + x_state @ W1[0:256]) -> H1 (kt 0..7) ----
        {
            float4v acc[2][2];
#pragma unroll
            for (int m = 0; m < 2; ++m)
#pragma unroll
                for (int t = 0; t < 2; ++t) acc[m][t] = uacc[m][t];
            if (lo_now) mm1p<8, 12, 8, 2>(aXh, aXl, XS, XLS, w1h, acc, p0, p1);
            else        mm1p<8, 12, 0, 2>(aXh, aXl, XS, XLS, w1h, acc, p0, p1);
            // prefetch L2's kt=0 B tiles before the barrier
            p0 = *(const short8*)(w2h);
            p1 = *(const short8*)(w2h + 16 * 512);
#pragma unroll
            for (int m = 0; m < 2; ++m)
#pragma unroll
                for (int t = 0; t < 2; ++t)
#pragma unroll
                    for (int r = 0; r < 4; ++r) {
                        float s = silu(acc[m][t][r]);
                        H1[(m * 16 + quad * 4 + r) * HS + w * 32 + t * 16 + col16] = f2bf(s);
                    }
        }
        __syncthreads();   // (a) h1 visible

        // ---- L2: silu(h1 @ W2 + b2) -> H2 ----
        {
            float4v acc[2][2];
#pragma unroll
            for (int m = 0; m < 2; ++m)
#pragma unroll
                for (int t = 0; t < 2; ++t) acc[m][t] = (float4v){b2f[t], b2f[t], b2f[t], b2f[t]};
            mm1p<16, 16, 0, 2>(aH1, aH1, HS, HS, w2h, acc, p0, p1);
            // prefetch L3's kt=0 B tile
            p0 = *(const short8*)(w3h);
#pragma unroll
            for (int m = 0; m < 2; ++m)
#pragma unroll
                for (int t = 0; t < 2; ++t)
#pragma unroll
                    for (int r = 0; r < 4; ++r) {
                        float s = silu(acc[m][t][r]);
                        H2[(m * 16 + quad * 4 + r) * HS + w * 32 + t * 16 + col16] = f2bf(s);
                    }
        }
        __syncthreads();   // (b) h2 visible; fences this step's H1 reads

        // ---- L3: h2 @ W3 + b3 -> st += f*dt; split-write state ----
        {
            float4v acc[2][1];
#pragma unroll
            for (int m = 0; m < 2; ++m) acc[m][0] = (float4v){b3f, b3f, b3f, b3f};
            mm1p<16, 16, 0, 1>(aH2, aH2, HS, HS, w3h, acc, p0, p0);
            // prefetch next step's L1 kt=0 B tiles
            p0 = *(const short8*)(w1h);
            p1 = *(const short8*)(w1h + 12 * 512);
#pragma unroll
            for (int m = 0; m < 2; ++m)
#pragma unroll
                for (int r = 0; r < 4; ++r) {
                    float v = st[m][r] + acc[m][0][r] * dt;
                    st[m][r] = v;
                    int row = m * 16 + quad * 4 + r;
                    int col = w * 16 + col16;
                    u16 h = f2bf(v);
                    xh[row * XS + col] = h;     // x not read since L1: safe
                    xl[row * XLS + col] = f2bf(v - bf2f(h));
                }
        }
        __syncthreads();   // (c) x(state) ready; fences this step's H2 reads
    }

    // ---- final state -> out ----
#pragma unroll
    for (int m = 0; m < 2; ++m)
#pragma unroll
        for (int r = 0; r < 4; ++r) {
            int row = m * 16 + quad * 4 + r;
            int col = w * 16 + col16;
            if (BF) ((u16*)outp)[(size_t)(r0 + row) * Sdim + col] = f2bf(st[m][r]);
            else    ((float*)outp)[(size_t)(r0 + row) * Sdim + col] = st[m][r];
        }
}

__global__ __launch_bounds__(1024, 4) void fused_ode(
    const void* state_raw, const void* user_raw,
    const void* b1r, const void* b2r, const void* b3r,
    const u16* __restrict__ wh, const int* __restrict__ flagp, void* outp) {

    __shared__ __align__(16) u16 xh[MT * XS];   // 25,088 B
    __shared__ __align__(16) u16 xl[MT * XLS];  // 16,896 B
    __shared__ __align__(16) u16 H1[MT * HS];   // 33,280 B
    __shared__ __align__(16) u16 H2[MT * HS];   // 33,280 B  -> 108,544 B

    if (*flagp)
        body<true >(state_raw, user_raw, b1r, b2r, b3r, wh, outp, xh, xl, H1, H2);
    else
        body<false>(state_raw, user_raw, b1r, b2r, b3r, wh, outp, xh, xl, H1, H2);
}

extern "C" void kernel_launch(void* const* d_in, const int* in_sizes, int n_in,
                              void* d_out, int out_size, void* d_ws, size_t ws_size,
                              hipStream_t stream) {
    u16* wh = (u16*)d_ws;
    int* flagp = (int*)((char*)d_ws + (size_t)NW * sizeof(u16));

    probe_dtype<<<1, 256, 0, stream>>>((const u16*)d_in[2], flagp);
    pack_all<<<288, 256, 0, stream>>>(d_in[2], d_in[4], d_in[6], wh, flagp);

    fused_ode<<<8192 / MT, 1024, 0, stream>>>(d_in[0], d_in[1], d_in[3], d_in[5], d_in[7],
                                              wh, flagp, d_out);
}

// Round 13
// 316.562 us; speedup vs baseline: 2.6673x; 2.6673x over previous
//
#include <hip/hip_runtime.h>

typedef __attribute__((ext_vector_type(8))) short short8;
typedef __attribute__((ext_vector_type(4))) float float4v;
typedef unsigned short u16;

#define Sdim 256
#define Udim 128
#define Hdim 512
#define MT   32       // rows per block
#define XS   392      // xh stride (u16): 384+8
#define XLS  264      // xl stride (state cols only): 256+8
#define HS   520      // h stride: 512+8
#define NW   589824   // total weight elements
#define W1_OFF 0
#define W2_OFF 196608
#define W3_OFF 458752
#define NSTEPS 21     // np-ref float32 h: floor(1/0.05f)=20 scaled + 1 unscaled

__device__ __forceinline__ float bf2f(u16 u) {
    union { unsigned int i; float f; } x; x.i = ((unsigned int)u) << 16; return x.f;
}
__device__ __forceinline__ u16 f2bf(float f) {
    union { float f; unsigned int i; } x; x.f = f;
    unsigned int r = x.i + 0x7FFFu + ((x.i >> 16) & 1u);  // RNE
    return (u16)(r >> 16);
}

// bf16 storage -> sane exponent fields; fp32 storage -> random mantissa u16s.
__device__ __forceinline__ int probe_local(const u16* __restrict__ w1, int tid) {
    __shared__ int cnt;
    if (tid == 0) cnt = 0;
    __syncthreads();
    if (tid < 256) {
        u16 u = w1[tid];
        int e = (u >> 7) & 0xFF;
        if ((u == 0) || (e >= 0x60 && e <= 0x8F)) atomicAdd(&cnt, 1);
    }
    __syncthreads();
    return (cnt >= 240) ? 1 : 0;   // 1 = bf16 inputs
}

// pack W (row-major KxN) into MFMA B-frag tiles, bf16 hi plane only
// (W-lo planes proven < 1 output-ulp: R8/R10 dropped them, absmax unchanged).
__device__ __forceinline__ void pack_body(const void* __restrict__ Wraw, u16* __restrict__ hi,
                                          int K, int N, int f, int bf) {
    int KT = K >> 5;
    int lane = f & 63, tile = f >> 6;
    int kt = tile % KT, nt = tile / KT;
    int k0 = kt * 32 + ((lane >> 4) << 3);
    int n  = nt * 16 + (lane & 15);
    short8 vh;
#pragma unroll
    for (int j = 0; j < 8; ++j) {
        float wv = bf ? bf2f(((const u16*)Wraw)[(size_t)(k0 + j) * N + n])
                      : ((const float*)Wraw)[(size_t)(k0 + j) * N + n];
        vh[j] = (short)f2bf(wv);
    }
    *reinterpret_cast<short8*>(hi + (size_t)f * 8) = vh;
}

// single prologue launch: every block self-probes dtype (no separate probe
// kernel); block 0 publishes the flag for fused_ode.
__global__ void pack_all(const void* __restrict__ W1, const void* __restrict__ W2,
                         const void* __restrict__ W3, u16* __restrict__ wh,
                         int* __restrict__ flagp) {
    int bf = probe_local((const u16*)W1, threadIdx.x);
    int b = blockIdx.x;
    if (b == 0 && threadIdx.x == 0) *flagp = bf;
    if (b < 96)
        pack_body(W1, wh + W1_OFF, 384, 512, b * 256 + threadIdx.x, bf);
    else if (b < 224)
        pack_body(W2, wh + W2_OFF, 512, 512, (b - 96) * 256 + threadIdx.x, bf);
    else
        pack_body(W3, wh + W3_OFF, 512, 256, (b - 224) * 256 + threadIdx.x, bf);
}

#define MFMA __builtin_amdgcn_mfma_f32_16x16x32_bf16

// Compiler-scheduled layer GEMM. unroll 2 ONLY — R7/R9/R12 all proved that
// deeper manual ILP (explicit dbuf, register pinning, unroll 4) lowers to
// scratch (WRITE_SIZE 8 MB -> 215-572 MB) and regresses 2-5x.
// kt runs [KT0, KT); A hi (2 msubs) [+ A lo for kt<KTL, reusing Bh].
template<int KT0, int KT, int KTB, int KTL, int NT>
__device__ __forceinline__ void mm1(const u16* ah, const u16* al, const int as, const int als,
                                    const u16* __restrict__ wh, float4v acc[2][NT]) {
#pragma unroll 2
    for (int kt = KT0; kt < KT; ++kt) {
        short8 A0 = *(const short8*)(ah + kt * 32);
        short8 A1 = *(const short8*)(ah + 16 * as + kt * 32);
        short8 A0l, A1l;
        if (kt < KTL) {
            A0l = *(const short8*)(al + kt * 32);
            A1l = *(const short8*)(al + 16 * als + kt * 32);
        }
#pragma unroll
        for (int t = 0; t < NT; ++t) {
            short8 Bh = *(const short8*)(wh + (size_t)(t * KTB + kt) * 512);
            acc[0][t] = MFMA(A0, Bh, acc[0][t], 0, 0, 0);
            acc[1][t] = MFMA(A1, Bh, acc[1][t], 0, 0, 0);
            if (kt < KTL) {     // x-lo correction reuses Bh — no extra load
                acc[0][t] = MFMA(A0l, Bh, acc[0][t], 0, 0, 0);
                acc[1][t] = MFMA(A1l, Bh, acc[1][t], 0, 0, 0);
            }
        }
    }
}

__device__ __forceinline__ float silu(float v) {
    // v_rcp_f32 rel err ~2^-22, far below the bf16 rounding applied after.
    return v * __builtin_amdgcn_rcpf(1.0f + __expf(-v));
}

template<bool BF>
__device__ __forceinline__ void body(
    const void* state_raw, const void* user_raw,
    const void* b1r, const void* b2r, const void* b3r,
    const u16* __restrict__ wh_all, void* outp,
    u16* xh, u16* xl, u16* H1, u16* H2) {

    const int tid = threadIdx.x, w = tid >> 6, lane = tid & 63;   // 16 waves
    const int col16 = lane & 15, quad = lane >> 4;
    const int r0 = blockIdx.x * MT;

    // ---- one-time: user params -> xh cols 256..383 (hi only) ----
    if (tid < 512) {
        int row = tid >> 4;
        int c8 = (tid & 15) * 8;
        if (BF) {
            short8 v = *(const short8*)((const u16*)user_raw + (size_t)(r0 + row) * Udim + c8);
            *(short8*)(xh + row * XS + Sdim + c8) = v;
        } else {
            const float* up = (const float*)user_raw + (size_t)(r0 + row) * Udim + c8;
            short8 v;
#pragma unroll
            for (int j = 0; j < 8; ++j) v[j] = (short)f2bf(up[j]);
            *(short8*)(xh + row * XS + Sdim + c8) = v;
        }
    }
    // ---- biases (C-layout: depend on col only) ----
    float b1f[2], b2f[2], b3f;
#pragma unroll
    for (int t = 0; t < 2; ++t) {
        int i = w * 32 + t * 16 + col16;
        b1f[t] = BF ? bf2f(((const u16*)b1r)[i]) : ((const float*)b1r)[i];
        b2f[t] = BF ? bf2f(((const u16*)b2r)[i]) : ((const float*)b2r)[i];
    }
    {
        int i = w * 16 + col16;
        b3f = BF ? bf2f(((const u16*)b3r)[i]) : ((const float*)b3r)[i];
    }
    // ---- state: fp32 regs (C-layout, wave owns 16 cols) + hi/lo split ----
    float st[2][4];
#pragma unroll
    for (int m = 0; m < 2; ++m)
#pragma unroll
        for (int r = 0; r < 4; ++r) {
            int row = m * 16 + quad * 4 + r;
            int col = w * 16 + col16;
            float v = BF ? bf2f(((const u16*)state_raw)[(size_t)(r0 + row) * Sdim + col])
                         : ((const float*)state_raw)[(size_t)(r0 + row) * Sdim + col];
            st[m][r] = v;
            u16 h = f2bf(v);
            xh[row * XS + col] = h;
            xl[row * XLS + col] = f2bf(v - bf2f(h));
        }
    __syncthreads();

    const u16* w1h = wh_all + W1_OFF + (size_t)(w * 2) * 12 * 512 + lane * 8;
    const u16* w2h = wh_all + W2_OFF + (size_t)(w * 2) * 16 * 512 + lane * 8;
    const u16* w3h = wh_all + W3_OFF + (size_t)(w)     * 16 * 512 + lane * 8;

    const u16* aXh = xh + col16 * XS + quad * 8;
    const u16* aXl = xl + col16 * XLS + quad * 8;
    const u16* aH1 = H1 + col16 * HS + quad * 8;
    const u16* aH2 = H2 + col16 * HS + quad * 8;

    // ---- step-invariant: uacc = b1 + user@W1[256:384] (kt 8..11), hoisted ----
    float4v uacc[2][2];
#pragma unroll
    for (int m = 0; m < 2; ++m)
#pragma unroll
        for (int t = 0; t < 2; ++t) uacc[m][t] = (float4v){b1f[t], b1f[t], b1f[t], b1f[t]};
    mm1<8, 12, 12, 0, 2>(aXh, aXh, XS, XS, w1h, uacc);

    for (int step = 0; step < NSTEPS; ++step) {
        const float dt = (step == NSTEPS - 1) ? 1.0f : 0.05f;
        // x-lo read at full significance only in step 0 and the unscaled
        // final step; middle steps enter x-lo * 0.05 (total ~0.01, inside margin).
        const bool lo_now = (step == 0) || (step == NSTEPS - 1);

        // ---- L1: silu(uacc + x_state @ W1[0:256]) -> H1 (kt 0..7) ----
        {
            float4v acc[2][2];
#pragma unroll
            for (int m = 0; m < 2; ++m)
#pragma unroll
                for (int t = 0; t < 2; ++t) acc[m][t] = uacc[m][t];
            if (lo_now) mm1<0, 8, 12, 8, 2>(aXh, aXl, XS, XLS, w1h, acc);
            else        mm1<0, 8, 12, 0, 2>(aXh, aXl, XS, XLS, w1h, acc);
#pragma unroll
            for (int m = 0; m < 2; ++m)
#pragma unroll
                for (int t = 0; t < 2; ++t)
#pragma unroll
                    for (int r = 0; r < 4; ++r) {
                        float s = silu(acc[m][t][r]);
                        H1[(m * 16 + quad * 4 + r) * HS + w * 32 + t * 16 + col16] = f2bf(s);
                    }
        }
        __syncthreads();   // (a) h1 visible

        // ---- L2: silu(h1 @ W2 + b2) -> H2 ----
        {
            float4v acc[2][2];
#pragma unroll
            for (int m = 0; m < 2; ++m)
#pragma unroll
                for (int t = 0; t < 2; ++t) acc[m][t] = (float4v){b2f[t], b2f[t], b2f[t], b2f[t]};
            mm1<0, 16, 16, 0, 2>(aH1, aH1, HS, HS, w2h, acc);
#pragma unroll
            for (int m = 0; m < 2; ++m)
#pragma unroll
                for (int t = 0; t < 2; ++t)
#pragma unroll
                    for (int r = 0; r < 4; ++r) {
                        float s = silu(acc[m][t][r]);
                        H2[(m * 16 + quad * 4 + r) * HS + w * 32 + t * 16 + col16] = f2bf(s);
                    }
        }
        __syncthreads();   // (b) h2 visible; fences this step's H1 reads

        // ---- L3: h2 @ W3 + b3 -> st += f*dt; split-write state (skip on the
        //      final step: nothing reads x afterwards — out comes from st). ----
        {
            float4v acc[2][1];
#pragma unroll
            for (int m = 0; m < 2; ++m) acc[m][0] = (float4v){b3f, b3f, b3f, b3f};
            mm1<0, 16, 16, 0, 1>(aH2, aH2, HS, HS, w3h, acc);
#pragma unroll
            for (int m = 0; m < 2; ++m)
#pragma unroll
                for (int r = 0; r < 4; ++r) {
                    float v = st[m][r] + acc[m][0][r] * dt;
                    st[m][r] = v;
                    if (step < NSTEPS - 1) {
                        int row = m * 16 + quad * 4 + r;
                        int col = w * 16 + col16;
                        u16 h = f2bf(v);
                        xh[row * XS + col] = h;     // x not read since L1: safe
                        xl[row * XLS + col] = f2bf(v - bf2f(h));
                    }
                }
        }
        __syncthreads();   // (c) x(state) ready; fences this step's H2 reads
    }

    // ---- final state -> out ----
#pragma unroll
    for (int m = 0; m < 2; ++m)
#pragma unroll
        for (int r = 0; r < 4; ++r) {
            int row = m * 16 + quad * 4 + r;
            int col = w * 16 + col16;
            if (BF) ((u16*)outp)[(size_t)(r0 + row) * Sdim + col] = f2bf(st[m][r]);
            else    ((float*)outp)[(size_t)(r0 + row) * Sdim + col] = st[m][r];
        }
}

__global__ __launch_bounds__(1024, 4) void fused_ode(
    const void* state_raw, const void* user_raw,
    const void* b1r, const void* b2r, const void* b3r,
    const u16* __restrict__ wh, const int* __restrict__ flagp, void* outp) {

    __shared__ __align__(16) u16 xh[MT * XS];   // 25,088 B
    __shared__ __align__(16) u16 xl[MT * XLS];  // 16,896 B
    __shared__ __align__(16) u16 H1[MT * HS];   // 33,280 B
    __shared__ __align__(16) u16 H2[MT * HS];   // 33,280 B  -> 108,544 B

    if (*flagp)
        body<true >(state_raw, user_raw, b1r, b2r, b3r, wh, outp, xh, xl, H1, H2);
    else
        body<false>(state_raw, user_raw, b1r, b2r, b3r, wh, outp, xh, xl, H1, H2);
}

extern "C" void kernel_launch(void* const* d_in, const int* in_sizes, int n_in,
                              void* d_out, int out_size, void* d_ws, size_t ws_size,
                              hipStream_t stream) {
    u16* wh = (u16*)d_ws;
    int* flagp = (int*)((char*)d_ws + (size_t)NW * sizeof(u16));

    pack_all<<<288, 256, 0, stream>>>(d_in[2], d_in[4], d_in[6], wh, flagp);

    fused_ode<<<8192 / MT, 1024, 0, stream>>>(d_in[0], d_in[1], d_in[3], d_in[5], d_in[7],
                                              wh, flagp, d_out);
}